// Round 1
// baseline (468.685 us; speedup 1.0000x reference)
//
#include <hip/hip_runtime.h>
#include <hip/hip_bf16.h>

// GCN 2-layer forward, f32 throughout.
// Pipeline:
//   deg_init -> deg_count(atomic) -> dinv
//   gemm1 (x@W1) -> init1 (self-loop + bias) -> agg1 (edge atomics)
//   gemm2 (relu(out1)@W2) -> init2 -> agg2 -> relu(out)

#define N_FEAT_IN 128
#define N_HID 64
#define N_CLS 40

__global__ void k_deg_init(float* deg, int n) {
    int i = blockIdx.x * blockDim.x + threadIdx.x;
    if (i < n) deg[i] = 1.0f;  // self-loop contributes 1
}

__global__ void k_deg_count(const int* __restrict__ ei, float* deg, int E) {
    int e = blockIdx.x * blockDim.x + threadIdx.x;
    if (e < E) atomicAdd(&deg[ei[E + e]], 1.0f);  // dst row
}

__global__ void k_dinv(float* deg, int n) {
    int i = blockIdx.x * blockDim.x + threadIdx.x;
    if (i < n) deg[i] = 1.0f / sqrtf(deg[i]);  // deg >= 1 always (self-loop)
}

// h1[n][64] = x[n][128] @ W1[128][64]
__global__ __launch_bounds__(256) void k_gemm1(const float* __restrict__ x,
                                               const float* __restrict__ W,
                                               float* __restrict__ h, int n) {
    __shared__ float Wl[N_FEAT_IN * N_HID];  // 32 KB
    for (int i = threadIdx.x; i < N_FEAT_IN * N_HID; i += 256) Wl[i] = W[i];
    __syncthreads();
    int node = blockIdx.x * 4 + (threadIdx.x >> 6);
    int c = threadIdx.x & 63;
    if (node >= n) return;
    const float* xr = x + (size_t)node * N_FEAT_IN;
    float acc = 0.f;
#pragma unroll
    for (int k = 0; k < N_FEAT_IN; ++k) acc += xr[k] * Wl[k * N_HID + c];
    h[(size_t)node * N_HID + c] = acc;
}

// h2[n][40] = relu(out1[n][64]) @ W2[64][40]
__global__ __launch_bounds__(320) void k_gemm2(const float* __restrict__ out1,
                                               const float* __restrict__ W,
                                               float* __restrict__ h2, int n) {
    __shared__ float Wl[N_HID * N_CLS];  // 10 KB
    for (int i = threadIdx.x; i < N_HID * N_CLS; i += 320) Wl[i] = W[i];
    __syncthreads();
    int node = blockIdx.x * 8 + threadIdx.x / N_CLS;
    int c = threadIdx.x % N_CLS;
    if (node >= n) return;
    const float* r = out1 + (size_t)node * N_HID;
    float acc = 0.f;
#pragma unroll
    for (int k = 0; k < N_HID; ++k) acc += fmaxf(r[k], 0.f) * Wl[k * N_CLS + c];
    h2[(size_t)node * N_CLS + c] = acc;
}

// out[n][F] = h[n][F] * dinv[n]^2 + b[F]   (self-loop term + bias)
template <int F>
__global__ void k_init(const float* __restrict__ h, const float* __restrict__ dinv,
                       const float* __restrict__ b, float* __restrict__ out, int n) {
    int idx = blockIdx.x * blockDim.x + threadIdx.x;
    if (idx >= n * F) return;
    int node = idx / F;
    int f = idx - node * F;
    float di = dinv[node];
    out[idx] = h[idx] * di * di + b[f];
}

// out[dst][F] += h[src][F] * dinv[src]*dinv[dst]   over all edges
template <int F>
__global__ void k_agg(const int* __restrict__ ei, const float* __restrict__ dinv,
                      const float* __restrict__ h, float* __restrict__ out, int E) {
    long long idx = (long long)blockIdx.x * blockDim.x + threadIdx.x;
    int e = (int)(idx / F);
    int f = (int)(idx - (long long)e * F);
    if (e >= E) return;
    int s = ei[e];
    int d = ei[E + e];
    float nm = dinv[s] * dinv[d];
    atomicAdd(&out[(size_t)d * F + f], h[(size_t)s * F + f] * nm);
}

__global__ void k_relu(float* out, int n) {
    int i = blockIdx.x * blockDim.x + threadIdx.x;
    if (i < n) out[i] = fmaxf(out[i], 0.f);
}

extern "C" void kernel_launch(void* const* d_in, const int* in_sizes, int n_in,
                              void* d_out, int out_size, void* d_ws, size_t ws_size,
                              hipStream_t stream) {
    const float* x = (const float*)d_in[0];
    const int* ei = (const int*)d_in[1];
    const float* W1 = (const float*)d_in[2];
    const float* b1 = (const float*)d_in[3];
    const float* W2 = (const float*)d_in[4];
    const float* b2 = (const float*)d_in[5];
    float* out = (float*)d_out;

    int n = in_sizes[0] / N_FEAT_IN;  // 50000
    int E = in_sizes[1] / 2;          // 800000

    // workspace layout (bytes, 1KB-aligned)
    char* ws = (char*)d_ws;
    float* dinv = (float*)(ws);                    // n floats        (200 KB)
    float* h1 = (float*)(ws + 200704);             // n*64 floats     (12.8 MB)
    float* out1 = (float*)(ws + 13000704);         // n*64 floats     (12.8 MB)
    float* h2 = (float*)(ws + 25800704);           // n*40 floats     (8 MB)

    const int B = 256;
    // 1) degree + dinv
    k_deg_init<<<(n + B - 1) / B, B, 0, stream>>>(dinv, n);
    k_deg_count<<<(E + B - 1) / B, B, 0, stream>>>(ei, dinv, E);
    k_dinv<<<(n + B - 1) / B, B, 0, stream>>>(dinv, n);

    // 2) layer 1
    k_gemm1<<<(n + 3) / 4, 256, 0, stream>>>(x, W1, h1, n);
    {
        long long tot = (long long)n * N_HID;
        k_init<N_HID><<<(int)((tot + B - 1) / B), B, 0, stream>>>(h1, dinv, b1, out1, n);
        long long etot = (long long)E * N_HID;
        k_agg<N_HID><<<(int)((etot + B - 1) / B), B, 0, stream>>>(ei, dinv, h1, out1, E);
    }

    // 3) layer 2 (relu fused into gemm2 input load)
    k_gemm2<<<(n + 7) / 8, 320, 0, stream>>>(out1, W2, h2, n);
    {
        long long tot = (long long)n * N_CLS;
        k_init<N_CLS><<<(int)((tot + B - 1) / B), B, 0, stream>>>(h2, dinv, b2, out, n);
        long long etot = (long long)E * N_CLS;
        k_agg<N_CLS><<<(int)((etot + B - 1) / B), B, 0, stream>>>(ei, dinv, h2, out, E);
        long long ot = (long long)n * N_CLS;
        k_relu<<<(int)((ot + B - 1) / B), B, 0, stream>>>(out, (int)ot);
    }
}

// Round 2
// 304.977 us; speedup vs baseline: 1.5368x; 1.5368x over previous
//
#include <hip/hip_runtime.h>
#include <hip/hip_bf16.h>

// GCN 2-layer forward, f32.
// CSR build (histogram -> scan -> scatter) + per-node wave gather aggregation.

#define N_FEAT_IN 128
#define N_HID 64
#define N_CLS 40

__global__ void k_zero(int* a, int n) {
    int i = blockIdx.x * blockDim.x + threadIdx.x;
    if (i < n) a[i] = 0;
}

__global__ void k_deg_count(const int* __restrict__ ei, int* deg, int E) {
    int e = blockIdx.x * blockDim.x + threadIdx.x;
    if (e < E) atomicAdd(&deg[ei[E + e]], 1);  // dst row
}

__global__ void k_dinv(const int* __restrict__ deg, float* dinv, int n) {
    int i = blockIdx.x * blockDim.x + threadIdx.x;
    if (i < n) dinv[i] = 1.0f / sqrtf((float)(deg[i] + 1));  // +1 = self-loop
}

__global__ void k_scan1(const int* __restrict__ deg, int* incl, int* blksum, int n) {
    __shared__ int s[256];
    int i = blockIdx.x * 256 + threadIdx.x;
    int v = (i < n) ? deg[i] : 0;
    s[threadIdx.x] = v;
    __syncthreads();
    for (int off = 1; off < 256; off <<= 1) {
        int t = (threadIdx.x >= off) ? s[threadIdx.x - off] : 0;
        __syncthreads();
        s[threadIdx.x] += t;
        __syncthreads();
    }
    if (i < n) incl[i] = s[threadIdx.x];
    if (threadIdx.x == 255) blksum[blockIdx.x] = s[255];
}

__global__ void k_scan2(const int* __restrict__ blksum, int* blkoff, int* row_start,
                        int nb, int n) {
    if (blockIdx.x == 0 && threadIdx.x == 0) {
        int run = 0;
        for (int b = 0; b < nb; ++b) { blkoff[b] = run; run += blksum[b]; }
        row_start[n] = run;  // == E
    }
}

__global__ void k_scan3(const int* __restrict__ incl, const int* __restrict__ deg,
                        const int* __restrict__ blkoff, int* row_start, int n) {
    int i = blockIdx.x * 256 + threadIdx.x;
    if (i < n) row_start[i] = incl[i] - deg[i] + blkoff[blockIdx.x];
}

__global__ void k_scatter(const int* __restrict__ ei, const float* __restrict__ dinv,
                          const int* __restrict__ row_start, int* cursor,
                          int* __restrict__ csr_src, float* __restrict__ csr_nrm, int E) {
    int e = blockIdx.x * blockDim.x + threadIdx.x;
    if (e >= E) return;
    int s = ei[e], d = ei[E + e];
    int pos = row_start[d] + atomicAdd(&cursor[d], 1);
    csr_src[pos] = s;
    csr_nrm[pos] = dinv[s] * dinv[d];
}

// h1[n][64] = x[n][128] @ W1[128][64]
__global__ __launch_bounds__(256) void k_gemm1(const float* __restrict__ x,
                                               const float* __restrict__ W,
                                               float* __restrict__ h, int n) {
    __shared__ float Wl[N_FEAT_IN * N_HID];  // 32 KB
    for (int i = threadIdx.x; i < N_FEAT_IN * N_HID; i += 256) Wl[i] = W[i];
    __syncthreads();
    int node = blockIdx.x * 4 + (threadIdx.x >> 6);
    int c = threadIdx.x & 63;
    if (node >= n) return;
    const float* xr = x + (size_t)node * N_FEAT_IN;
    float acc = 0.f;
#pragma unroll
    for (int k = 0; k < N_FEAT_IN; ++k) acc += xr[k] * Wl[k * N_HID + c];
    h[(size_t)node * N_HID + c] = acc;
}

// h2[n][40] = out1[n][64] @ W2[64][40]   (out1 already ReLU'd)
__global__ __launch_bounds__(320) void k_gemm2(const float* __restrict__ out1,
                                               const float* __restrict__ W,
                                               float* __restrict__ h2, int n) {
    __shared__ float Wl[N_HID * N_CLS];  // 10 KB
    for (int i = threadIdx.x; i < N_HID * N_CLS; i += 320) Wl[i] = W[i];
    __syncthreads();
    int node = blockIdx.x * 8 + threadIdx.x / N_CLS;
    int c = threadIdx.x % N_CLS;
    if (node >= n) return;
    const float* r = out1 + (size_t)node * N_HID;
    float acc = 0.f;
#pragma unroll
    for (int k = 0; k < N_HID; ++k) acc += r[k] * Wl[k * N_CLS + c];
    h2[(size_t)node * N_CLS + c] = acc;
}

// out[node][f] = relu( h[node][f]*dinv[node]^2 + b[f] + sum_e h[src_e][f]*nrm_e )
template <int F>
__global__ __launch_bounds__(256) void k_aggr(const int* __restrict__ row_start,
                                              const int* __restrict__ csr_src,
                                              const float* __restrict__ csr_nrm,
                                              const float* __restrict__ dinv,
                                              const float* __restrict__ h,
                                              const float* __restrict__ b,
                                              float* __restrict__ out, int n) {
    __shared__ int Ss[4 * 64];
    __shared__ float Sn[4 * 64];
    int wv = threadIdx.x >> 6, lane = threadIdx.x & 63;
    int node = blockIdx.x * 4 + wv;
    if (node >= n) return;
    float acc = 0.f;
    if (F == 64 || lane < F) {
        float di = dinv[node];
        acc = h[(size_t)node * F + lane] * di * di + b[lane];
    }
    int beg = row_start[node], end = row_start[node + 1];
    for (int j0 = beg; j0 < end; j0 += 64) {
        int j = j0 + lane;
        if (j < end) {
            Ss[wv * 64 + lane] = csr_src[j];
            Sn[wv * 64 + lane] = csr_nrm[j];
        }
        int cnt = min(64, end - j0);
        for (int t = 0; t < cnt; ++t) {
            int s = __builtin_amdgcn_readfirstlane(Ss[wv * 64 + t]);
            float nm = Sn[wv * 64 + t];
            if (F == 64 || lane < F) acc += h[(size_t)s * F + lane] * nm;
        }
    }
    if (F == 64 || lane < F)
        out[(size_t)node * F + lane] = fmaxf(acc, 0.f);
}

extern "C" void kernel_launch(void* const* d_in, const int* in_sizes, int n_in,
                              void* d_out, int out_size, void* d_ws, size_t ws_size,
                              hipStream_t stream) {
    const float* x = (const float*)d_in[0];
    const int* ei = (const int*)d_in[1];
    const float* W1 = (const float*)d_in[2];
    const float* b1 = (const float*)d_in[3];
    const float* W2 = (const float*)d_in[4];
    const float* b2 = (const float*)d_in[5];
    float* out = (float*)d_out;

    int n = in_sizes[0] / N_FEAT_IN;  // 50000
    int E = in_sizes[1] / 2;          // 800000
    int nb = (n + 255) / 256;

    char* ws = (char*)d_ws;
    float* dinv      = (float*)(ws + 0);
    int*   deg_i     = (int*)  (ws + 200704);
    int*   row_start = (int*)  (ws + 401408);
    int*   cursor    = (int*)  (ws + 602112);
    int*   incl      = (int*)  (ws + 802816);
    int*   blksum    = (int*)  (ws + 1003520);
    int*   blkoff    = (int*)  (ws + 1004544);
    int*   csr_src   = (int*)  (ws + 1005568);
    float* csr_nrm   = (float*)(ws + 4206592);
    float* h1        = (float*)(ws + 7407616);
    float* out1      = (float*)(ws + 20208128);
    float* h2        = h1;  // h1 dead after agg1

    const int B = 256;
    k_zero<<<(n + B - 1) / B, B, 0, stream>>>(deg_i, n);
    k_zero<<<(n + B - 1) / B, B, 0, stream>>>(cursor, n);
    k_deg_count<<<(E + B - 1) / B, B, 0, stream>>>(ei, deg_i, E);
    k_dinv<<<(n + B - 1) / B, B, 0, stream>>>(deg_i, dinv, n);

    k_scan1<<<nb, 256, 0, stream>>>(deg_i, incl, blksum, n);
    k_scan2<<<1, 64, 0, stream>>>(blksum, blkoff, row_start, nb, n);
    k_scan3<<<nb, 256, 0, stream>>>(incl, deg_i, blkoff, row_start, n);
    k_scatter<<<(E + B - 1) / B, B, 0, stream>>>(ei, dinv, row_start, cursor,
                                                 csr_src, csr_nrm, E);

    k_gemm1<<<(n + 3) / 4, 256, 0, stream>>>(x, W1, h1, n);
    k_aggr<N_HID><<<(n + 3) / 4, 256, 0, stream>>>(row_start, csr_src, csr_nrm,
                                                   dinv, h1, b1, out1, n);
    k_gemm2<<<(n + 7) / 8, 320, 0, stream>>>(out1, W2, h2, n);
    k_aggr<N_CLS><<<(n + 3) / 4, 256, 0, stream>>>(row_start, csr_src, csr_nrm,
                                                   dinv, h2, b2, out, n);
}

// Round 3
// 251.975 us; speedup vs baseline: 1.8600x; 1.2103x over previous
//
#include <hip/hip_runtime.h>
#include <hip/hip_bf16.h>

// GCN 2-layer forward, f32.
// CSR build (histogram -> scan -> scatter) + per-node wave gather aggregation.
// Round 2: register-tiled GEMMs (4x4 per thread, LDS-staged operands).

#define N_FEAT_IN 128
#define N_HID 64
#define N_CLS 40

__global__ void k_zero2(int* a, int* b, int n) {
    int i = blockIdx.x * blockDim.x + threadIdx.x;
    if (i < n) { a[i] = 0; b[i] = 0; }
}

__global__ void k_deg_count(const int* __restrict__ ei, int* deg, int E) {
    int e = blockIdx.x * blockDim.x + threadIdx.x;
    if (e < E) atomicAdd(&deg[ei[E + e]], 1);  // dst row
}

__global__ void k_dinv(const int* __restrict__ deg, float* dinv, int n) {
    int i = blockIdx.x * blockDim.x + threadIdx.x;
    if (i < n) dinv[i] = 1.0f / sqrtf((float)(deg[i] + 1));  // +1 = self-loop
}

__global__ void k_scan1(const int* __restrict__ deg, int* incl, int* blksum, int n) {
    __shared__ int s[256];
    int i = blockIdx.x * 256 + threadIdx.x;
    int v = (i < n) ? deg[i] : 0;
    s[threadIdx.x] = v;
    __syncthreads();
    for (int off = 1; off < 256; off <<= 1) {
        int t = (threadIdx.x >= off) ? s[threadIdx.x - off] : 0;
        __syncthreads();
        s[threadIdx.x] += t;
        __syncthreads();
    }
    if (i < n) incl[i] = s[threadIdx.x];
    if (threadIdx.x == 255) blksum[blockIdx.x] = s[255];
}

__global__ void k_scan2(const int* __restrict__ blksum, int* blkoff, int* row_start,
                        int nb, int n) {
    if (blockIdx.x == 0 && threadIdx.x == 0) {
        int run = 0;
        for (int b = 0; b < nb; ++b) { blkoff[b] = run; run += blksum[b]; }
        row_start[n] = run;  // == E
    }
}

__global__ void k_scan3(const int* __restrict__ incl, const int* __restrict__ deg,
                        const int* __restrict__ blkoff, int* row_start, int n) {
    int i = blockIdx.x * 256 + threadIdx.x;
    if (i < n) row_start[i] = incl[i] - deg[i] + blkoff[blockIdx.x];
}

__global__ void k_scatter(const int* __restrict__ ei, const float* __restrict__ dinv,
                          const int* __restrict__ row_start, int* cursor,
                          int* __restrict__ csr_src, float* __restrict__ csr_nrm, int E) {
    int e = blockIdx.x * blockDim.x + threadIdx.x;
    if (e >= E) return;
    int s = ei[e], d = ei[E + e];
    int pos = row_start[d] + atomicAdd(&cursor[d], 1);
    csr_src[pos] = s;
    csr_nrm[pos] = dinv[s] * dinv[d];
}

// ---------- tiled GEMM1: h[64n][64] = x[64n][128] @ W[128][64] ----------
// block = 256 threads -> 64 nodes x 64 cols, 4x4 register tile per thread.
__global__ __launch_bounds__(256, 2) void k_gemm1(const float* __restrict__ x,
                                                  const float* __restrict__ W,
                                                  float* __restrict__ h, int n) {
    __shared__ float Wl[N_FEAT_IN * N_HID];   // 32 KB
    __shared__ float Xs[64 * 132];            // 33.8 KB (pad 128->132: 2-way bank alias, free)
    int t = threadIdx.x;
    int node0 = blockIdx.x * 64;
    // W: 8192 floats, 8 float4 per thread, coalesced
    for (int i = t * 4; i < N_FEAT_IN * N_HID; i += 1024)
        *(float4*)&Wl[i] = *(const float4*)&W[i];
    // X tile: 64 rows x 128 = 2048 float4, 8 per thread, coalesced
#pragma unroll
    for (int i = 0; i < 8; ++i) {
        int r = (t >> 5) + i * 8;
        int c4 = t & 31;
        int gr = node0 + r;
        float4 v = (gr < n) ? *(const float4*)&x[(size_t)gr * N_FEAT_IN + c4 * 4]
                            : make_float4(0.f, 0.f, 0.f, 0.f);
        *(float4*)&Xs[r * 132 + c4 * 4] = v;
    }
    __syncthreads();
    int tn = t & 15;   // node group: nodes tn + 16*i
    int tc = t >> 4;   // col group:  cols 4*tc + j
    float acc[4][4] = {};
    for (int k = 0; k < N_FEAT_IN; k += 4) {
        float4 xa[4], wb[4];
#pragma unroll
        for (int i = 0; i < 4; ++i)
            xa[i] = *(float4*)&Xs[(tn + 16 * i) * 132 + k];
#pragma unroll
        for (int kk = 0; kk < 4; ++kk)
            wb[kk] = *(float4*)&Wl[(k + kk) * N_HID + tc * 4];
#pragma unroll
        for (int kk = 0; kk < 4; ++kk)
#pragma unroll
            for (int i = 0; i < 4; ++i)
#pragma unroll
                for (int j = 0; j < 4; ++j)
                    acc[i][j] += ((const float*)&xa[i])[kk] * ((const float*)&wb[kk])[j];
    }
#pragma unroll
    for (int i = 0; i < 4; ++i) {
        int gr = node0 + tn + 16 * i;
        if (gr < n) {
            float4 v = make_float4(acc[i][0], acc[i][1], acc[i][2], acc[i][3]);
            *(float4*)&h[(size_t)gr * N_HID + tc * 4] = v;
        }
    }
}

// ---------- tiled GEMM2: h2[64n][40] = out1[64n][64] @ W2[64][40] ----------
__global__ __launch_bounds__(256, 2) void k_gemm2(const float* __restrict__ out1,
                                                  const float* __restrict__ W,
                                                  float* __restrict__ h2, int n) {
    __shared__ float Wl[N_HID * N_CLS];   // 10.2 KB
    __shared__ float Xs[64 * 68];         // 17.4 KB (pad 64->68)
    int t = threadIdx.x;
    int node0 = blockIdx.x * 64;
    for (int i = t * 4; i < N_HID * N_CLS; i += 1024)
        *(float4*)&Wl[i] = *(const float4*)&W[i];
#pragma unroll
    for (int i = 0; i < 4; ++i) {
        int r = (t >> 4) + i * 16;
        int c4 = t & 15;
        int gr = node0 + r;
        float4 v = (gr < n) ? *(const float4*)&out1[(size_t)gr * N_HID + c4 * 4]
                            : make_float4(0.f, 0.f, 0.f, 0.f);
        *(float4*)&Xs[r * 68 + c4 * 4] = v;
    }
    __syncthreads();
    int tn = t & 15;
    int tc = t >> 4;     // only tc<10 compute (40 cols)
    if (tc < 10) {
        float acc[4][4] = {};
        for (int k = 0; k < N_HID; k += 4) {
            float4 xa[4], wb[4];
#pragma unroll
            for (int i = 0; i < 4; ++i)
                xa[i] = *(float4*)&Xs[(tn + 16 * i) * 68 + k];
#pragma unroll
            for (int kk = 0; kk < 4; ++kk)
                wb[kk] = *(float4*)&Wl[(k + kk) * N_CLS + tc * 4];
#pragma unroll
            for (int kk = 0; kk < 4; ++kk)
#pragma unroll
                for (int i = 0; i < 4; ++i)
#pragma unroll
                    for (int j = 0; j < 4; ++j)
                        acc[i][j] += ((const float*)&xa[i])[kk] * ((const float*)&wb[kk])[j];
        }
#pragma unroll
        for (int i = 0; i < 4; ++i) {
            int gr = node0 + tn + 16 * i;
            if (gr < n) {
                float4 v = make_float4(acc[i][0], acc[i][1], acc[i][2], acc[i][3]);
                *(float4*)&h2[(size_t)gr * N_CLS + tc * 4] = v;
            }
        }
    }
}

// out[node][f] = relu( h[node][f]*dinv[node]^2 + b[f] + sum_e h[src_e][f]*nrm_e )
template <int F>
__global__ __launch_bounds__(256) void k_aggr(const int* __restrict__ row_start,
                                              const int* __restrict__ csr_src,
                                              const float* __restrict__ csr_nrm,
                                              const float* __restrict__ dinv,
                                              const float* __restrict__ h,
                                              const float* __restrict__ b,
                                              float* __restrict__ out, int n) {
    __shared__ int Ss[4 * 64];
    __shared__ float Sn[4 * 64];
    int wv = threadIdx.x >> 6, lane = threadIdx.x & 63;
    int node = blockIdx.x * 4 + wv;
    if (node >= n) return;
    float acc = 0.f;
    if (F == 64 || lane < F) {
        float di = dinv[node];
        acc = h[(size_t)node * F + lane] * di * di + b[lane];
    }
    int beg = row_start[node], end = row_start[node + 1];
    for (int j0 = beg; j0 < end; j0 += 64) {
        int j = j0 + lane;
        if (j < end) {
            Ss[wv * 64 + lane] = csr_src[j];
            Sn[wv * 64 + lane] = csr_nrm[j];
        }
        int cnt = min(64, end - j0);
        for (int t = 0; t < cnt; ++t) {
            int s = __builtin_amdgcn_readfirstlane(Ss[wv * 64 + t]);
            float nm = Sn[wv * 64 + t];
            if (F == 64 || lane < F) acc += h[(size_t)s * F + lane] * nm;
        }
    }
    if (F == 64 || lane < F)
        out[(size_t)node * F + lane] = fmaxf(acc, 0.f);
}

extern "C" void kernel_launch(void* const* d_in, const int* in_sizes, int n_in,
                              void* d_out, int out_size, void* d_ws, size_t ws_size,
                              hipStream_t stream) {
    const float* x = (const float*)d_in[0];
    const int* ei = (const int*)d_in[1];
    const float* W1 = (const float*)d_in[2];
    const float* b1 = (const float*)d_in[3];
    const float* W2 = (const float*)d_in[4];
    const float* b2 = (const float*)d_in[5];
    float* out = (float*)d_out;

    int n = in_sizes[0] / N_FEAT_IN;  // 50000
    int E = in_sizes[1] / 2;          // 800000
    int nb = (n + 255) / 256;

    char* ws = (char*)d_ws;
    float* dinv      = (float*)(ws + 0);
    int*   deg_i     = (int*)  (ws + 200704);
    int*   row_start = (int*)  (ws + 401408);
    int*   cursor    = (int*)  (ws + 602112);
    int*   incl      = (int*)  (ws + 802816);
    int*   blksum    = (int*)  (ws + 1003520);
    int*   blkoff    = (int*)  (ws + 1004544);
    int*   csr_src   = (int*)  (ws + 1005568);
    float* csr_nrm   = (float*)(ws + 4206592);
    float* h1        = (float*)(ws + 7407616);
    float* out1      = (float*)(ws + 20208128);
    float* h2        = h1;  // h1 dead after agg1

    const int B = 256;
    k_zero2<<<(n + B - 1) / B, B, 0, stream>>>(deg_i, cursor, n);
    k_deg_count<<<(E + B - 1) / B, B, 0, stream>>>(ei, deg_i, E);
    k_dinv<<<(n + B - 1) / B, B, 0, stream>>>(deg_i, dinv, n);

    k_scan1<<<nb, 256, 0, stream>>>(deg_i, incl, blksum, n);
    k_scan2<<<1, 64, 0, stream>>>(blksum, blkoff, row_start, nb, n);
    k_scan3<<<nb, 256, 0, stream>>>(incl, deg_i, blkoff, row_start, n);
    k_scatter<<<(E + B - 1) / B, B, 0, stream>>>(ei, dinv, row_start, cursor,
                                                 csr_src, csr_nrm, E);

    int gb = (n + 63) / 64;
    k_gemm1<<<gb, 256, 0, stream>>>(x, W1, h1, n);
    k_aggr<N_HID><<<(n + 3) / 4, 256, 0, stream>>>(row_start, csr_src, csr_nrm,
                                                   dinv, h1, b1, out1, n);
    k_gemm2<<<gb, 256, 0, stream>>>(out1, W2, h2, n);
    k_aggr<N_CLS><<<(n + 3) / 4, 256, 0, stream>>>(row_start, csr_src, csr_nrm,
                                                   dinv, h2, b2, out, n);
}

// Round 4
// 197.677 us; speedup vs baseline: 2.3710x; 1.2747x over previous
//
#include <hip/hip_runtime.h>
#include <hip/hip_bf16.h>

// GCN 2-layer forward, f32.
// Round 3: layer-2 re-association (aggregate at F=64, then 64->40 GEMM with
// fused bias+relu) + 4-edges-in-flight float4 gather aggregation.

#define N_FEAT_IN 128
#define N_HID 64
#define N_CLS 40

__global__ void k_zero2(int* a, int* b, int n) {
    int i = blockIdx.x * blockDim.x + threadIdx.x;
    if (i < n) { a[i] = 0; b[i] = 0; }
}

__global__ void k_deg_count(const int* __restrict__ ei, int* deg, int E) {
    int e = blockIdx.x * blockDim.x + threadIdx.x;
    if (e < E) atomicAdd(&deg[ei[E + e]], 1);  // dst row
}

__global__ void k_dinv(const int* __restrict__ deg, float* dinv, int n) {
    int i = blockIdx.x * blockDim.x + threadIdx.x;
    if (i < n) dinv[i] = 1.0f / sqrtf((float)(deg[i] + 1));  // +1 = self-loop
}

__global__ void k_scan1(const int* __restrict__ deg, int* incl, int* blksum, int n) {
    __shared__ int s[256];
    int i = blockIdx.x * 256 + threadIdx.x;
    int v = (i < n) ? deg[i] : 0;
    s[threadIdx.x] = v;
    __syncthreads();
    for (int off = 1; off < 256; off <<= 1) {
        int t = (threadIdx.x >= off) ? s[threadIdx.x - off] : 0;
        __syncthreads();
        s[threadIdx.x] += t;
        __syncthreads();
    }
    if (i < n) incl[i] = s[threadIdx.x];
    if (threadIdx.x == 255) blksum[blockIdx.x] = s[255];
}

__global__ void k_scan2(const int* __restrict__ blksum, int* blkoff, int* row_start,
                        int nb, int n) {
    if (blockIdx.x == 0 && threadIdx.x == 0) {
        int run = 0;
        for (int b = 0; b < nb; ++b) { blkoff[b] = run; run += blksum[b]; }
        row_start[n] = run;  // == E
    }
}

__global__ void k_scan3(const int* __restrict__ incl, const int* __restrict__ deg,
                        const int* __restrict__ blkoff, int* row_start, int n) {
    int i = blockIdx.x * 256 + threadIdx.x;
    if (i < n) row_start[i] = incl[i] - deg[i] + blkoff[blockIdx.x];
}

__global__ void k_scatter(const int* __restrict__ ei, const float* __restrict__ dinv,
                          const int* __restrict__ row_start, int* cursor,
                          int* __restrict__ csr_src, float* __restrict__ csr_nrm, int E) {
    int e = blockIdx.x * blockDim.x + threadIdx.x;
    if (e >= E) return;
    int s = ei[e], d = ei[E + e];
    int pos = row_start[d] + atomicAdd(&cursor[d], 1);
    csr_src[pos] = s;
    csr_nrm[pos] = dinv[s] * dinv[d];
}

// ---------- tiled GEMM1: h[64n][64] = x[64n][128] @ W[128][64] ----------
__global__ __launch_bounds__(256, 2) void k_gemm1(const float* __restrict__ x,
                                                  const float* __restrict__ W,
                                                  float* __restrict__ h, int n) {
    __shared__ float Wl[N_FEAT_IN * N_HID];   // 32 KB
    __shared__ float Xs[64 * 132];            // 33.8 KB
    int t = threadIdx.x;
    int node0 = blockIdx.x * 64;
    for (int i = t * 4; i < N_FEAT_IN * N_HID; i += 1024)
        *(float4*)&Wl[i] = *(const float4*)&W[i];
#pragma unroll
    for (int i = 0; i < 8; ++i) {
        int r = (t >> 5) + i * 8;
        int c4 = t & 31;
        int gr = node0 + r;
        float4 v = (gr < n) ? *(const float4*)&x[(size_t)gr * N_FEAT_IN + c4 * 4]
                            : make_float4(0.f, 0.f, 0.f, 0.f);
        *(float4*)&Xs[r * 132 + c4 * 4] = v;
    }
    __syncthreads();
    int tn = t & 15;
    int tc = t >> 4;
    float acc[4][4] = {};
    for (int k = 0; k < N_FEAT_IN; k += 4) {
        float4 xa[4], wb[4];
#pragma unroll
        for (int i = 0; i < 4; ++i)
            xa[i] = *(float4*)&Xs[(tn + 16 * i) * 132 + k];
#pragma unroll
        for (int kk = 0; kk < 4; ++kk)
            wb[kk] = *(float4*)&Wl[(k + kk) * N_HID + tc * 4];
#pragma unroll
        for (int kk = 0; kk < 4; ++kk)
#pragma unroll
            for (int i = 0; i < 4; ++i)
#pragma unroll
                for (int j = 0; j < 4; ++j)
                    acc[i][j] += ((const float*)&xa[i])[kk] * ((const float*)&wb[kk])[j];
    }
#pragma unroll
    for (int i = 0; i < 4; ++i) {
        int gr = node0 + tn + 16 * i;
        if (gr < n) {
            float4 v = make_float4(acc[i][0], acc[i][1], acc[i][2], acc[i][3]);
            *(float4*)&h[(size_t)gr * N_HID + tc * 4] = v;
        }
    }
}

// ---------- fused final GEMM: out[64n][40] = relu(g2[64n][64] @ W2 + b2) ----------
__global__ __launch_bounds__(256, 2) void k_gemm2f(const float* __restrict__ g2,
                                                   const float* __restrict__ W,
                                                   const float* __restrict__ bias,
                                                   float* __restrict__ out, int n) {
    __shared__ float Wl[N_HID * N_CLS];   // 10.2 KB
    __shared__ float Xs[64 * 68];         // 17.4 KB
    int t = threadIdx.x;
    int node0 = blockIdx.x * 64;
    for (int i = t * 4; i < N_HID * N_CLS; i += 1024)
        *(float4*)&Wl[i] = *(const float4*)&W[i];
#pragma unroll
    for (int i = 0; i < 4; ++i) {
        int r = (t >> 4) + i * 16;
        int c4 = t & 15;
        int gr = node0 + r;
        float4 v = (gr < n) ? *(const float4*)&g2[(size_t)gr * N_HID + c4 * 4]
                            : make_float4(0.f, 0.f, 0.f, 0.f);
        *(float4*)&Xs[r * 68 + c4 * 4] = v;
    }
    __syncthreads();
    int tn = t & 15;
    int tc = t >> 4;
    if (tc < 10) {
        float acc[4][4] = {};
        for (int k = 0; k < N_HID; k += 4) {
            float4 xa[4], wb[4];
#pragma unroll
            for (int i = 0; i < 4; ++i)
                xa[i] = *(float4*)&Xs[(tn + 16 * i) * 68 + k];
#pragma unroll
            for (int kk = 0; kk < 4; ++kk)
                wb[kk] = *(float4*)&Wl[(k + kk) * N_CLS + tc * 4];
#pragma unroll
            for (int kk = 0; kk < 4; ++kk)
#pragma unroll
                for (int i = 0; i < 4; ++i)
#pragma unroll
                    for (int j = 0; j < 4; ++j)
                        acc[i][j] += ((const float*)&xa[i])[kk] * ((const float*)&wb[kk])[j];
        }
        float4 bv = *(const float4*)&bias[tc * 4];
#pragma unroll
        for (int i = 0; i < 4; ++i) {
            int gr = node0 + tn + 16 * i;
            if (gr < n) {
                float4 v = make_float4(fmaxf(acc[i][0] + bv.x, 0.f),
                                       fmaxf(acc[i][1] + bv.y, 0.f),
                                       fmaxf(acc[i][2] + bv.z, 0.f),
                                       fmaxf(acc[i][3] + bv.w, 0.f));
                *(float4*)&out[(size_t)gr * N_CLS + tc * 4] = v;
            }
        }
    }
}

// ---------- aggregation, F=64, 4 edges in flight ----------
// RELU_BIAS: out = relu(selfloop + bias + sum)  else: out = selfloop + sum
template <bool RELU_BIAS>
__global__ __launch_bounds__(256) void k_aggr64(const int* __restrict__ row_start,
                                                const int* __restrict__ csr_src,
                                                const float* __restrict__ csr_nrm,
                                                const float* __restrict__ dinv,
                                                const float* __restrict__ h,
                                                const float* __restrict__ b,
                                                float* __restrict__ out, int n) {
    __shared__ int Ss[4 * 64];
    __shared__ float Sn[4 * 64];
    int wv = threadIdx.x >> 6, lane = threadIdx.x & 63;
    int g = lane >> 4, l = lane & 15;
    int node = blockIdx.x * 4 + wv;
    if (node >= n) return;
    float4 acc = make_float4(0.f, 0.f, 0.f, 0.f);
    if (g == 0) {  // only group 0 holds the self-loop/bias term (reduce sums groups)
        float di = dinv[node];
        float s2 = di * di;
        float4 hv = *(const float4*)&h[(size_t)node * N_HID + l * 4];
        acc.x = hv.x * s2; acc.y = hv.y * s2; acc.z = hv.z * s2; acc.w = hv.w * s2;
        if (RELU_BIAS) {
            float4 bv = *(const float4*)&b[l * 4];
            acc.x += bv.x; acc.y += bv.y; acc.z += bv.z; acc.w += bv.w;
        }
    }
    int beg = row_start[node], end = row_start[node + 1];
    for (int j0 = beg; j0 < end; j0 += 64) {
        int j = j0 + lane;
        if (j < end) {
            Ss[wv * 64 + lane] = csr_src[j];
            Sn[wv * 64 + lane] = csr_nrm[j];
        }
        int cnt = min(64, end - j0);
        int t = 0;
        // 2x unrolled: 8 edges in flight across the wave
        for (; t + 8 <= cnt; t += 8) {
            int s1 = Ss[wv * 64 + t + g];
            float nm1 = Sn[wv * 64 + t + g];
            int s2 = Ss[wv * 64 + t + 4 + g];
            float nm2 = Sn[wv * 64 + t + 4 + g];
            float4 v1 = *(const float4*)&h[(size_t)s1 * N_HID + l * 4];
            float4 v2 = *(const float4*)&h[(size_t)s2 * N_HID + l * 4];
            acc.x += nm1 * v1.x; acc.y += nm1 * v1.y;
            acc.z += nm1 * v1.z; acc.w += nm1 * v1.w;
            acc.x += nm2 * v2.x; acc.y += nm2 * v2.y;
            acc.z += nm2 * v2.z; acc.w += nm2 * v2.w;
        }
        for (; t < cnt; t += 4) {
            int e = t + g;
            if (e < cnt) {
                int s = Ss[wv * 64 + e];
                float nm = Sn[wv * 64 + e];
                float4 v = *(const float4*)&h[(size_t)s * N_HID + l * 4];
                acc.x += nm * v.x; acc.y += nm * v.y;
                acc.z += nm * v.z; acc.w += nm * v.w;
            }
        }
    }
    // cross-group butterfly reduce (groups 0..3 -> all)
    acc.x += __shfl_xor(acc.x, 16); acc.y += __shfl_xor(acc.y, 16);
    acc.z += __shfl_xor(acc.z, 16); acc.w += __shfl_xor(acc.w, 16);
    acc.x += __shfl_xor(acc.x, 32); acc.y += __shfl_xor(acc.y, 32);
    acc.z += __shfl_xor(acc.z, 32); acc.w += __shfl_xor(acc.w, 32);
    if (g == 0) {
        float4 o = acc;
        if (RELU_BIAS) {
            o.x = fmaxf(o.x, 0.f); o.y = fmaxf(o.y, 0.f);
            o.z = fmaxf(o.z, 0.f); o.w = fmaxf(o.w, 0.f);
        }
        *(float4*)&out[(size_t)node * N_HID + l * 4] = o;
    }
}

extern "C" void kernel_launch(void* const* d_in, const int* in_sizes, int n_in,
                              void* d_out, int out_size, void* d_ws, size_t ws_size,
                              hipStream_t stream) {
    const float* x = (const float*)d_in[0];
    const int* ei = (const int*)d_in[1];
    const float* W1 = (const float*)d_in[2];
    const float* b1 = (const float*)d_in[3];
    const float* W2 = (const float*)d_in[4];
    const float* b2 = (const float*)d_in[5];
    float* out = (float*)d_out;

    int n = in_sizes[0] / N_FEAT_IN;  // 50000
    int E = in_sizes[1] / 2;          // 800000
    int nb = (n + 255) / 256;

    char* ws = (char*)d_ws;
    float* dinv      = (float*)(ws + 0);
    int*   deg_i     = (int*)  (ws + 200704);
    int*   row_start = (int*)  (ws + 401408);
    int*   cursor    = (int*)  (ws + 602112);
    int*   incl      = (int*)  (ws + 802816);
    int*   blksum    = (int*)  (ws + 1003520);
    int*   blkoff    = (int*)  (ws + 1004544);
    int*   csr_src   = (int*)  (ws + 1005568);
    float* csr_nrm   = (float*)(ws + 4206592);
    float* h1        = (float*)(ws + 7407616);   // n*64 f32; reused as g2
    float* out1      = (float*)(ws + 20208128);  // n*64 f32
    float* g2        = h1;                       // h1 dead after agg1

    const int B = 256;
    k_zero2<<<(n + B - 1) / B, B, 0, stream>>>(deg_i, cursor, n);
    k_deg_count<<<(E + B - 1) / B, B, 0, stream>>>(ei, deg_i, E);
    k_dinv<<<(n + B - 1) / B, B, 0, stream>>>(deg_i, dinv, n);

    k_scan1<<<nb, 256, 0, stream>>>(deg_i, incl, blksum, n);
    k_scan2<<<1, 64, 0, stream>>>(blksum, blkoff, row_start, nb, n);
    k_scan3<<<nb, 256, 0, stream>>>(incl, deg_i, blkoff, row_start, n);
    k_scatter<<<(E + B - 1) / B, B, 0, stream>>>(ei, dinv, row_start, cursor,
                                                 csr_src, csr_nrm, E);

    int gb = (n + 63) / 64;
    k_gemm1<<<gb, 256, 0, stream>>>(x, W1, h1, n);
    // layer 1 aggregate: out1 = relu(selfloop + b1 + sum)
    k_aggr64<true><<<(n + 3) / 4, 256, 0, stream>>>(row_start, csr_src, csr_nrm,
                                                    dinv, h1, b1, out1, n);
    // layer 2 aggregate first (re-associated): g2 = selfloop + sum over out1
    k_aggr64<false><<<(n + 3) / 4, 256, 0, stream>>>(row_start, csr_src, csr_nrm,
                                                     dinv, out1, nullptr, g2, n);
    // then fused 64->40 GEMM + bias + relu
    k_gemm2f<<<gb, 256, 0, stream>>>(g2, W2, b2, out, n);
}

// Round 5
// 170.578 us; speedup vs baseline: 2.7476x; 1.1589x over previous
//
#include <hip/hip_runtime.h>
#include <hip/hip_bf16.h>

// GCN 2-layer forward, f32.
// Round 4: factorized symmetric norm (no csr_nrm, pre-scaled feature rows),
// GEMM1 fused with scatter (latency overlap), parallel scan2, dinv folded
// into scan1. CSR stores src indices only.

#define N_FEAT_IN 128
#define N_HID 64
#define N_CLS 40

__global__ void k_zero2(int* a, int* b, int n) {
    int i = blockIdx.x * blockDim.x + threadIdx.x;
    if (i < n) { a[i] = 0; b[i] = 0; }
}

__global__ void k_deg_count(const int* __restrict__ ei, int* deg, int E) {
    int e = blockIdx.x * blockDim.x + threadIdx.x;
    if (e < E) atomicAdd(&deg[ei[E + e]], 1);  // dst row
}

// block-inclusive scan of deg + per-block sums; also dinv = 1/sqrt(deg+1)
__global__ void k_scan1(const int* __restrict__ deg, float* __restrict__ dinv,
                        int* incl, int* blksum, int n) {
    __shared__ int s[256];
    int i = blockIdx.x * 256 + threadIdx.x;
    int v = (i < n) ? deg[i] : 0;
    if (i < n) dinv[i] = 1.0f / sqrtf((float)(v + 1));  // +1 = self-loop
    s[threadIdx.x] = v;
    __syncthreads();
    for (int off = 1; off < 256; off <<= 1) {
        int t = (threadIdx.x >= off) ? s[threadIdx.x - off] : 0;
        __syncthreads();
        s[threadIdx.x] += t;
        __syncthreads();
    }
    if (i < n) incl[i] = s[threadIdx.x];
    if (threadIdx.x == 255) blksum[blockIdx.x] = s[255];
}

// single-block parallel scan of block sums (nb <= 256)
__global__ void k_scan2(const int* __restrict__ blksum, int* blkoff, int* row_start,
                        int nb, int n) {
    __shared__ int s[256];
    int t = threadIdx.x;
    int v = (t < nb) ? blksum[t] : 0;
    s[t] = v;
    __syncthreads();
    for (int off = 1; off < 256; off <<= 1) {
        int u = (t >= off) ? s[t - off] : 0;
        __syncthreads();
        s[t] += u;
        __syncthreads();
    }
    if (t < nb) blkoff[t] = s[t] - v;  // exclusive
    if (t == 255) row_start[n] = s[255];  // == E
}

__global__ void k_scan3(const int* __restrict__ incl, const int* __restrict__ deg,
                        const int* __restrict__ blkoff, int* row_start, int n) {
    int i = blockIdx.x * 256 + threadIdx.x;
    if (i < n) row_start[i] = incl[i] - deg[i] + blkoff[blockIdx.x];
}

// ---------- fused: blocks [0,gb) = GEMM1 (h1s = (x@W1)*dinv), rest = scatter ----------
__global__ __launch_bounds__(256) void k_g1_scatter(
    const float* __restrict__ x, const float* __restrict__ W,
    const float* __restrict__ dinv, float* __restrict__ hs, int n, int gb,
    const int* __restrict__ ei, const int* __restrict__ row_start,
    int* cursor, int* __restrict__ csr_src, int E) {
    __shared__ float Wl[64 * 64];   // 16 KB (half of W1 per phase)
    __shared__ float Xs[64 * 68];   // 17.4 KB
    int t = threadIdx.x;
    if (blockIdx.x >= gb) {
        int e = (blockIdx.x - gb) * 256 + t;
        if (e < E) {
            int s = ei[e], d = ei[E + e];
            int pos = row_start[d] + atomicAdd(&cursor[d], 1);
            csr_src[pos] = s;
        }
        return;
    }
    int node0 = blockIdx.x * 64;
    int tn = t & 15;
    int tc = t >> 4;
    float acc[4][4] = {};
    for (int p = 0; p < 2; ++p) {
#pragma unroll
        for (int i = 0; i < 4; ++i) {
            int r = (t >> 4) + 16 * i;
            int c4 = t & 15;
            *(float4*)&Wl[r * 64 + c4 * 4] =
                *(const float4*)&W[(p * 64 + r) * N_HID + c4 * 4];
            int gr = node0 + r;
            float4 v = (gr < n)
                ? *(const float4*)&x[(size_t)gr * N_FEAT_IN + p * 64 + c4 * 4]
                : make_float4(0.f, 0.f, 0.f, 0.f);
            *(float4*)&Xs[r * 68 + c4 * 4] = v;
        }
        __syncthreads();
        for (int k = 0; k < 64; k += 4) {
            float4 xa[4], wb[4];
#pragma unroll
            for (int i = 0; i < 4; ++i)
                xa[i] = *(float4*)&Xs[(tn + 16 * i) * 68 + k];
#pragma unroll
            for (int kk = 0; kk < 4; ++kk)
                wb[kk] = *(float4*)&Wl[(k + kk) * 64 + tc * 4];
#pragma unroll
            for (int kk = 0; kk < 4; ++kk)
#pragma unroll
                for (int i = 0; i < 4; ++i)
#pragma unroll
                    for (int j = 0; j < 4; ++j)
                        acc[i][j] += ((const float*)&xa[i])[kk] * ((const float*)&wb[kk])[j];
        }
        __syncthreads();
    }
#pragma unroll
    for (int i = 0; i < 4; ++i) {
        int gr = node0 + tn + 16 * i;
        if (gr < n) {
            float di = dinv[gr];
            float4 v = make_float4(acc[i][0] * di, acc[i][1] * di,
                                   acc[i][2] * di, acc[i][3] * di);
            *(float4*)&hs[(size_t)gr * N_HID + tc * 4] = v;
        }
    }
}

// ---------- aggregation, F=64, factorized norm ----------
// acc = hs[node] + sum_e hs[src_e]     (hs rows pre-scaled by dinv[src])
// L1:  out = relu(dinv[node]*acc + b) * dinv[node]   (pre-scaled for layer 2)
// L2:  out = dinv[node]*acc                          (fed to final GEMM)
template <bool L1>
__global__ __launch_bounds__(256) void k_aggr64(const int* __restrict__ row_start,
                                                const int* __restrict__ csr_src,
                                                const float* __restrict__ dinv,
                                                const float* __restrict__ hs,
                                                const float* __restrict__ b,
                                                float* __restrict__ out, int n) {
    __shared__ int Ss[4 * 64];
    int wv = threadIdx.x >> 6, lane = threadIdx.x & 63;
    int g = lane >> 4, l = lane & 15;
    int node = blockIdx.x * 4 + wv;
    if (node >= n) return;
    float4 acc = make_float4(0.f, 0.f, 0.f, 0.f);
    if (g == 0)  // self-loop term joins the sum with unit weight
        acc = *(const float4*)&hs[(size_t)node * N_HID + l * 4];
    int beg = row_start[node], end = row_start[node + 1];
    for (int j0 = beg; j0 < end; j0 += 64) {
        int j = j0 + lane;
        if (j < end) Ss[wv * 64 + lane] = csr_src[j];
        int cnt = min(64, end - j0);
        int t = 0;
        for (; t + 8 <= cnt; t += 8) {  // 8 edges in flight per wave
            int s1 = Ss[wv * 64 + t + g];
            int s2 = Ss[wv * 64 + t + 4 + g];
            float4 v1 = *(const float4*)&hs[(size_t)s1 * N_HID + l * 4];
            float4 v2 = *(const float4*)&hs[(size_t)s2 * N_HID + l * 4];
            acc.x += v1.x + v2.x; acc.y += v1.y + v2.y;
            acc.z += v1.z + v2.z; acc.w += v1.w + v2.w;
        }
        for (; t < cnt; t += 4) {
            int e = t + g;
            if (e < cnt) {
                int s = Ss[wv * 64 + e];
                float4 v = *(const float4*)&hs[(size_t)s * N_HID + l * 4];
                acc.x += v.x; acc.y += v.y; acc.z += v.z; acc.w += v.w;
            }
        }
    }
    acc.x += __shfl_xor(acc.x, 16); acc.y += __shfl_xor(acc.y, 16);
    acc.z += __shfl_xor(acc.z, 16); acc.w += __shfl_xor(acc.w, 16);
    acc.x += __shfl_xor(acc.x, 32); acc.y += __shfl_xor(acc.y, 32);
    acc.z += __shfl_xor(acc.z, 32); acc.w += __shfl_xor(acc.w, 32);
    if (g == 0) {
        float di = dinv[node];
        float4 o;
        if (L1) {
            float4 bv = *(const float4*)&b[l * 4];
            o.x = fmaxf(di * acc.x + bv.x, 0.f) * di;
            o.y = fmaxf(di * acc.y + bv.y, 0.f) * di;
            o.z = fmaxf(di * acc.z + bv.z, 0.f) * di;
            o.w = fmaxf(di * acc.w + bv.w, 0.f) * di;
        } else {
            o.x = di * acc.x; o.y = di * acc.y;
            o.z = di * acc.z; o.w = di * acc.w;
        }
        *(float4*)&out[(size_t)node * N_HID + l * 4] = o;
    }
}

// ---------- fused final GEMM: out[64n][40] = relu(g2d[64n][64] @ W2 + b2) ----------
__global__ __launch_bounds__(256, 2) void k_gemm2f(const float* __restrict__ g2,
                                                   const float* __restrict__ W,
                                                   const float* __restrict__ bias,
                                                   float* __restrict__ out, int n) {
    __shared__ float Wl[N_HID * N_CLS];   // 10.2 KB
    __shared__ float Xs[64 * 68];         // 17.4 KB
    int t = threadIdx.x;
    int node0 = blockIdx.x * 64;
    for (int i = t * 4; i < N_HID * N_CLS; i += 1024)
        *(float4*)&Wl[i] = *(const float4*)&W[i];
#pragma unroll
    for (int i = 0; i < 4; ++i) {
        int r = (t >> 4) + i * 16;
        int c4 = t & 15;
        int gr = node0 + r;
        float4 v = (gr < n) ? *(const float4*)&g2[(size_t)gr * N_HID + c4 * 4]
                            : make_float4(0.f, 0.f, 0.f, 0.f);
        *(float4*)&Xs[r * 68 + c4 * 4] = v;
    }
    __syncthreads();
    int tn = t & 15;
    int tc = t >> 4;
    if (tc < 10) {
        float acc[4][4] = {};
        for (int k = 0; k < N_HID; k += 4) {
            float4 xa[4], wb[4];
#pragma unroll
            for (int i = 0; i < 4; ++i)
                xa[i] = *(float4*)&Xs[(tn + 16 * i) * 68 + k];
#pragma unroll
            for (int kk = 0; kk < 4; ++kk)
                wb[kk] = *(float4*)&Wl[(k + kk) * N_CLS + tc * 4];
#pragma unroll
            for (int kk = 0; kk < 4; ++kk)
#pragma unroll
                for (int i = 0; i < 4; ++i)
#pragma unroll
                    for (int j = 0; j < 4; ++j)
                        acc[i][j] += ((const float*)&xa[i])[kk] * ((const float*)&wb[kk])[j];
        }
        float4 bv = *(const float4*)&bias[tc * 4];
#pragma unroll
        for (int i = 0; i < 4; ++i) {
            int gr = node0 + tn + 16 * i;
            if (gr < n) {
                float4 v = make_float4(fmaxf(acc[i][0] + bv.x, 0.f),
                                       fmaxf(acc[i][1] + bv.y, 0.f),
                                       fmaxf(acc[i][2] + bv.z, 0.f),
                                       fmaxf(acc[i][3] + bv.w, 0.f));
                *(float4*)&out[(size_t)gr * N_CLS + tc * 4] = v;
            }
        }
    }
}

extern "C" void kernel_launch(void* const* d_in, const int* in_sizes, int n_in,
                              void* d_out, int out_size, void* d_ws, size_t ws_size,
                              hipStream_t stream) {
    const float* x = (const float*)d_in[0];
    const int* ei = (const int*)d_in[1];
    const float* W1 = (const float*)d_in[2];
    const float* b1 = (const float*)d_in[3];
    const float* W2 = (const float*)d_in[4];
    const float* b2 = (const float*)d_in[5];
    float* out = (float*)d_out;

    int n = in_sizes[0] / N_FEAT_IN;  // 50000
    int E = in_sizes[1] / 2;          // 800000
    int nb = (n + 255) / 256;

    char* ws = (char*)d_ws;
    float* dinv      = (float*)(ws + 0);
    int*   deg_i     = (int*)  (ws + 200704);
    int*   row_start = (int*)  (ws + 401408);
    int*   cursor    = (int*)  (ws + 602112);
    int*   incl      = (int*)  (ws + 802816);
    int*   blksum    = (int*)  (ws + 1003520);
    int*   blkoff    = (int*)  (ws + 1004544);
    int*   csr_src   = (int*)  (ws + 1005568);   // E i32
    float* h1s       = (float*)(ws + 7407616);   // n*64 f32; reused as g2d
    float* out1s     = (float*)(ws + 20208128);  // n*64 f32
    float* g2d       = h1s;                      // h1s dead after aggr1

    const int B = 256;
    k_zero2<<<(n + B - 1) / B, B, 0, stream>>>(deg_i, cursor, n);
    k_deg_count<<<(E + B - 1) / B, B, 0, stream>>>(ei, deg_i, E);
    k_scan1<<<nb, 256, 0, stream>>>(deg_i, dinv, incl, blksum, n);
    k_scan2<<<1, 256, 0, stream>>>(blksum, blkoff, row_start, nb, n);
    k_scan3<<<nb, 256, 0, stream>>>(incl, deg_i, blkoff, row_start, n);

    int gb = (n + 63) / 64;
    int sb = (E + 255) / 256;
    k_g1_scatter<<<gb + sb, 256, 0, stream>>>(x, W1, dinv, h1s, n, gb,
                                              ei, row_start, cursor, csr_src, E);

    k_aggr64<true><<<(n + 3) / 4, 256, 0, stream>>>(row_start, csr_src, dinv,
                                                    h1s, b1, out1s, n);
    k_aggr64<false><<<(n + 3) / 4, 256, 0, stream>>>(row_start, csr_src, dinv,
                                                     out1s, nullptr, g2d, n);
    k_gemm2f<<<gb, 256, 0, stream>>>(g2d, W2, b2, out, n);
}